// Round 1
// baseline (1078.119 us; speedup 1.0000x reference)
//
#include <hip/hip_runtime.h>

typedef unsigned short u16;
typedef unsigned int u32;
typedef __attribute__((ext_vector_type(8))) short short8;
typedef __attribute__((ext_vector_type(4))) float floatx4;

#define E_ 1024
#define B_ 256
#define M_ 196
#define H_ 8
#define DH_ 128
#define MID_ 64

__device__ __forceinline__ u16 f2bf(float f){
  union { float f; u32 u; } v; v.f = f;
  return (u16)((v.u + (((v.u >> 16) & 1u) + 0x7fffu)) >> 16);
}
__device__ __forceinline__ float bf2f(u16 h){
  union { u32 u; float f; } v; v.u = ((u32)h) << 16;
  return v.f;
}

// ---------------------------------------------------------------------------
// Kernel 0: convert+transpose the 4 projection weight matrices to bf16 [col][k]
// so GEMM B-staging is contiguous 16B vector copies with zero conversion VALU.
// ---------------------------------------------------------------------------
__global__ __launch_bounds__(256) void wconv_kernel(
    const float* __restrict__ Wq, const float* __restrict__ Wk,
    const float* __restrict__ Wv1, const float* __restrict__ Wv2,
    u16* __restrict__ Wt)
{
  __shared__ u16 tile[64][72];
  const float* W = (blockIdx.z == 0) ? Wq : (blockIdx.z == 1) ? Wk
                 : (blockIdx.z == 2) ? Wv1 : Wv2;
  u16* out = Wt + (size_t)blockIdx.z * (E_ * E_);
  int k0 = blockIdx.x * 64, c0 = blockIdx.y * 64;
  int tx = threadIdx.x & 63, ty = threadIdx.x >> 6;
  #pragma unroll
  for (int i = 0; i < 16; i++){
    int k = ty * 16 + i;
    tile[k][tx] = f2bf(W[(size_t)(k0 + k) * E_ + c0 + tx]);
  }
  __syncthreads();
  #pragma unroll
  for (int i = 0; i < 16; i++){
    int c = ty * 16 + i;
    out[(size_t)(c0 + c) * E_ + k0 + tx] = tile[tx][c];
  }
}

// ---------------------------------------------------------------------------
// Kernel 1: fused GEMM + bias + celu + group-norm for all four projections.
// 128x128 tile, BK=32, 4 waves (2x2), 4x4 16x16x32 bf16 MFMA frags per wave.
// LDS row stride 56 bf16 (112 B): 16B-aligned for ds_read_b128, 2-way banks.
// Group == the block's 128-col tile, so groupnorm is a row reduction here.
// ---------------------------------------------------------------------------
__global__ __launch_bounds__(256, 2) void proj_kernel(
    const float* __restrict__ query, const float* __restrict__ key,
    const float* __restrict__ value1, const float* __restrict__ value2,
    const float* __restrict__ bq, const float* __restrict__ gqw, const float* __restrict__ gqb,
    const float* __restrict__ bk, const float* __restrict__ gkw, const float* __restrict__ gkb,
    const float* __restrict__ bv1, const float* __restrict__ gv1w, const float* __restrict__ gv1b,
    const float* __restrict__ bv2, const float* __restrict__ gv2w, const float* __restrict__ gv2b,
    const u16* __restrict__ Wt,
    u16* __restrict__ qout, u16* __restrict__ kout,
    u16* __restrict__ v1out, u16* __restrict__ v2out)
{
  __shared__ u16 a_lds[128 * 56];
  __shared__ u16 b_lds[128 * 56];
  __shared__ float s_sum[256];
  __shared__ float s_sq[256];

  const int tid = threadIdx.x;
  const int w = tid >> 6, lane = tid & 63, qd = lane >> 4, lr = lane & 15;
  const int wm = w >> 1, wn = w & 1;

  const int mtb = blockIdx.y;
  const float* X; const float *bias, *gw, *gb; u16* out; int row0, matsel;
  if (mtb < 392)      { X = key;    bias = bk;  gw = gkw;  gb = gkb;  out = kout;  row0 = mtb * 128;         matsel = 1; }
  else if (mtb < 784) { X = value2; bias = bv2; gw = gv2w; gb = gv2b; out = v2out; row0 = (mtb - 392) * 128; matsel = 3; }
  else if (mtb < 786) { X = query;  bias = bq;  gw = gqw;  gb = gqb;  out = qout;  row0 = (mtb - 784) * 128; matsel = 0; }
  else                { X = value1; bias = bv1; gw = gv1w; gb = gv1b; out = v1out; row0 = (mtb - 786) * 128; matsel = 2; }
  const int col0 = blockIdx.x * 128;

  const int arow = tid >> 3, ac8 = tid & 7;         // A: 8 threads/row, float4 each
  const float* Aptr = X + (size_t)(row0 + arow) * E_ + ac8 * 4;
  const int nn = tid & 127, half = tid >> 7;        // B: thread owns col nn, half of k
  const u16* Bptr = Wt + (size_t)matsel * (E_ * E_) + (size_t)(col0 + nn) * E_ + half * 16;

  floatx4 acc[4][4];
  #pragma unroll
  for (int i = 0; i < 4; i++)
    #pragma unroll
    for (int j = 0; j < 4; j++){
      floatx4 z = {0.f, 0.f, 0.f, 0.f};
      acc[i][j] = z;
    }

  float4 ar[4];
  uint4 br0, br1;
  #pragma unroll
  for (int i = 0; i < 4; i++) ar[i] = *(const float4*)(Aptr + (size_t)i * 32 * E_);
  br0 = *(const uint4*)(Bptr);
  br1 = *(const uint4*)(Bptr + 8);

  for (int kt = 0; kt < 32; kt++){
    __syncthreads();
    #pragma unroll
    for (int i = 0; i < 4; i++){
      uint2 u;
      u.x = (u32)f2bf(ar[i].x) | ((u32)f2bf(ar[i].y) << 16);
      u.y = (u32)f2bf(ar[i].z) | ((u32)f2bf(ar[i].w) << 16);
      *(uint2*)&a_lds[(arow + 32 * i) * 56 + ac8 * 4] = u;
    }
    *(uint4*)&b_lds[nn * 56 + half * 16] = br0;
    *(uint4*)&b_lds[nn * 56 + half * 16 + 8] = br1;
    __syncthreads();
    if (kt < 31){
      int k0 = (kt + 1) * 32;
      #pragma unroll
      for (int i = 0; i < 4; i++) ar[i] = *(const float4*)(Aptr + (size_t)i * 32 * E_ + k0);
      br0 = *(const uint4*)(Bptr + k0);
      br1 = *(const uint4*)(Bptr + k0 + 8);
    }
    short8 afr[4], bfr[4];
    #pragma unroll
    for (int m2 = 0; m2 < 4; m2++)
      afr[m2] = *(const short8*)&a_lds[(wm * 64 + m2 * 16 + lr) * 56 + qd * 8];
    #pragma unroll
    for (int nt = 0; nt < 4; nt++)
      bfr[nt] = *(const short8*)&b_lds[(wn * 64 + nt * 16 + lr) * 56 + qd * 8];
    #pragma unroll
    for (int m2 = 0; m2 < 4; m2++)
      #pragma unroll
      for (int nt = 0; nt < 4; nt++)
        acc[m2][nt] = __builtin_amdgcn_mfma_f32_16x16x32_bf16(afr[m2], bfr[nt], acc[m2][nt], 0, 0, 0);
  }

  // Epilogue: bias + celu (in place), per-row mean/var over the 128-col group.
  float biasv[4], gwv[4], gbv[4];
  #pragma unroll
  for (int nt = 0; nt < 4; nt++){
    int c = col0 + wn * 64 + nt * 16 + lr;
    biasv[nt] = bias[c]; gwv[nt] = gw[c]; gbv[nt] = gb[c];
  }
  #pragma unroll
  for (int m2 = 0; m2 < 4; m2++){
    float sr[4] = {0, 0, 0, 0}, sq[4] = {0, 0, 0, 0};
    #pragma unroll
    for (int nt = 0; nt < 4; nt++){
      #pragma unroll
      for (int r = 0; r < 4; r++){
        float x = acc[m2][nt][r] + biasv[nt];
        x = (x > 0.f) ? x : 1.3f * expm1f(x * (1.0f / 1.3f));
        acc[m2][nt][r] = x;
        sr[r] += x; sq[r] += x * x;
      }
    }
    #pragma unroll
    for (int r = 0; r < 4; r++){
      float a = sr[r], b2 = sq[r];
      #pragma unroll
      for (int off = 1; off < 16; off <<= 1){
        a  += __shfl_xor(a, off, 64);
        b2 += __shfl_xor(b2, off, 64);
      }
      if (lr == 0){
        int row = wm * 64 + m2 * 16 + qd * 4 + r;
        s_sum[row * 2 + wn] = a;
        s_sq [row * 2 + wn] = b2;
      }
    }
  }
  __syncthreads();
  #pragma unroll
  for (int m2 = 0; m2 < 4; m2++){
    #pragma unroll
    for (int r = 0; r < 4; r++){
      int row = wm * 64 + m2 * 16 + qd * 4 + r;
      float s  = s_sum[row * 2] + s_sum[row * 2 + 1];
      float s2 = s_sq [row * 2] + s_sq [row * 2 + 1];
      float mean = s * 0.0078125f;
      float var  = s2 * 0.0078125f - mean * mean;
      float rstd = rsqrtf(var + 1e-5f);
      size_t base = (size_t)(row0 + row) * E_ + col0 + wn * 64;
      #pragma unroll
      for (int nt = 0; nt < 4; nt++){
        float o = (acc[m2][nt][r] - mean) * rstd * gwv[nt] + gbv[nt];
        out[base + nt * 16 + lr] = f2bf(o);
      }
    }
  }
}

// ---------------------------------------------------------------------------
// Kernel 2: per-(b,h) attention. att = q*k staged in LDS (bf16, stride 136),
// hidden = relu(att @ Wb + bb) via MFMA, never materialized: logits and masked
// hidden-sums reduced in-register. Masked softmax, v2 pooling, channel gate.
// ---------------------------------------------------------------------------
__global__ __launch_bounds__(256, 2) void attn_kernel(
    const u16* __restrict__ qproj, const u16* __restrict__ kproj,
    const u16* __restrict__ v1proj, const u16* __restrict__ v2proj,
    const int* __restrict__ mask,
    const float* __restrict__ Wb, const float* __restrict__ bb,
    const float* __restrict__ Ws, const float* __restrict__ bs,
    const float* __restrict__ Wc, const float* __restrict__ bc,
    float* __restrict__ outp)
{
  __shared__ u16 att[208 * 136];
  __shared__ u16 wbt[64 * 136];
  __shared__ float qv[128];
  __shared__ float mrow[208];
  __shared__ float logitv[208];
  __shared__ float hsum_l[4][64];
  __shared__ float wexpv[208];
  __shared__ float poolv[64];
  __shared__ float v2p[2][128];
  __shared__ float red[8];

  const int tid = threadIdx.x;
  const int w = tid >> 6, lane = tid & 63, qd = lane >> 4, lr = lane & 15;
  const int b = blockIdx.y, h = blockIdx.x;

  if (tid < 128) qv[tid] = bf2f(qproj[(size_t)b * E_ + h * DH_ + tid]);
  if (tid < 208) mrow[tid] = (tid < M_) ? (float)mask[b * M_ + tid] : 0.f;
  {
    int n = tid & 63, k0g = (tid >> 6) * 32;
    #pragma unroll
    for (int kk = 0; kk < 32; kk++)
      wbt[n * 136 + k0g + kk] = f2bf(Wb[(k0g + kk) * MID_ + n]);
  }
  __syncthreads();  // qv ready before att staging

  for (int c = tid; c < M_ * 32; c += 256){
    int row = c >> 5, d4 = (c & 31) * 4;
    uint2 u = *(const uint2*)&kproj[((size_t)(b * M_ + row)) * E_ + h * DH_ + d4];
    float x0 = bf2f((u16)(u.x & 0xffff)) * qv[d4 + 0];
    float x1 = bf2f((u16)(u.x >> 16))    * qv[d4 + 1];
    float x2 = bf2f((u16)(u.y & 0xffff)) * qv[d4 + 2];
    float x3 = bf2f((u16)(u.y >> 16))    * qv[d4 + 3];
    uint2 o;
    o.x = (u32)f2bf(x0) | ((u32)f2bf(x1) << 16);
    o.y = (u32)f2bf(x2) | ((u32)f2bf(x3) << 16);
    *(uint2*)&att[row * 136 + d4] = o;
  }
  for (int c = tid; c < 12 * 136; c += 256) att[M_ * 136 + c] = 0;  // zero pad rows
  __syncthreads();

  float wsv[4], bbv[4];
  #pragma unroll
  for (int nt = 0; nt < 4; nt++){ wsv[nt] = Ws[nt * 16 + lr]; bbv[nt] = bb[nt * 16 + lr]; }
  const float bsv = bs[0];
  float hs[4] = {0, 0, 0, 0};

  for (int mt = w; mt < 13; mt += 4){
    floatx4 hacc[4];
    #pragma unroll
    for (int nt = 0; nt < 4; nt++){ floatx4 z = {0.f, 0.f, 0.f, 0.f}; hacc[nt] = z; }
    #pragma unroll
    for (int kc = 0; kc < 4; kc++){
      short8 afr = *(const short8*)&att[(mt * 16 + lr) * 136 + kc * 32 + qd * 8];
      #pragma unroll
      for (int nt = 0; nt < 4; nt++){
        short8 bfr = *(const short8*)&wbt[(nt * 16 + lr) * 136 + kc * 32 + qd * 8];
        hacc[nt] = __builtin_amdgcn_mfma_f32_16x16x32_bf16(afr, bfr, hacc[nt], 0, 0, 0);
      }
    }
    float lp[4] = {0, 0, 0, 0};
    #pragma unroll
    for (int nt = 0; nt < 4; nt++){
      #pragma unroll
      for (int r = 0; r < 4; r++){
        float hv = hacc[nt][r] + bbv[nt];
        hv = fmaxf(hv, 0.f);
        lp[r] += hv * wsv[nt];
        hs[nt] += mrow[mt * 16 + qd * 4 + r] * hv;
      }
    }
    #pragma unroll
    for (int r = 0; r < 4; r++){
      float a = lp[r];
      #pragma unroll
      for (int off = 1; off < 16; off <<= 1) a += __shfl_xor(a, off, 64);
      if (lr == 0) logitv[mt * 16 + qd * 4 + r] = a + bsv;
    }
  }
  #pragma unroll
  for (int nt = 0; nt < 4; nt++){
    hs[nt] += __shfl_xor(hs[nt], 16, 64);
    hs[nt] += __shfl_xor(hs[nt], 32, 64);
  }
  if (lane < 16){
    #pragma unroll
    for (int nt = 0; nt < 4; nt++) hsum_l[w][nt * 16 + lane] = hs[nt];
  }
  __syncthreads();

  if (w == 0){
    float s = 0.f;
    for (int m = lane; m < M_; m += 64) s += mrow[m];
    #pragma unroll
    for (int off = 1; off < 64; off <<= 1) s += __shfl_xor(s, off, 64);
    if (lane == 0) red[0] = s;
  } else if (w == 1){
    float mx = -1e30f;
    for (int m = lane; m < M_; m += 64) if (mrow[m] > 0.5f) mx = fmaxf(mx, logitv[m]);
    #pragma unroll
    for (int off = 1; off < 64; off <<= 1) mx = fmaxf(mx, __shfl_xor(mx, off, 64));
    if (lane == 0) red[1] = mx;
  } else if (w == 2){
    if (lane < 64)
      poolv[lane] = hsum_l[0][lane] + hsum_l[1][lane] + hsum_l[2][lane] + hsum_l[3][lane];
  }
  __syncthreads();
  const float cnt = red[0], mx = red[1];
  if (tid < 208)
    wexpv[tid] = (tid < M_ && mrow[tid] > 0.5f) ? expf(logitv[tid] - mx) : 0.f;
  __syncthreads();
  if (w == 0){
    float s = 0.f;
    for (int m = lane; m < M_; m += 64) s += wexpv[m];
    #pragma unroll
    for (int off = 1; off < 64; off <<= 1) s += __shfl_xor(s, off, 64);
    if (lane == 0) red[2] = s;
  } else if (w == 1){
    if (lane < 64) poolv[lane] = poolv[lane] / cnt;
  }
  __syncthreads();
  const float S = red[2];

  {
    int halfsel = tid >> 7, d = tid & 127;
    float p = 0.f;
    for (int m = halfsel; m < M_; m += 2)
      p += wexpv[m] * bf2f(v2proj[((size_t)(b * M_ + m)) * E_ + h * DH_ + d]);
    v2p[halfsel][d] = p;
  }
  float acv = 0.f;
  if (tid < 128){
    float a = 0.f;
    for (int j = 0; j < 64; j++) a += poolv[j] * Wc[j * DH_ + tid];
    acv = 1.f / (1.f + expf(-(a + bc[tid])));
  }
  __syncthreads();
  if (tid < 128){
    float vp = (v2p[0][tid] + v2p[1][tid]) / S;
    float o = bf2f(v1proj[(size_t)b * E_ + h * DH_ + tid]) * vp * acv;
    outp[(size_t)b * E_ + h * DH_ + tid] = o;
  }
}

// ---------------------------------------------------------------------------
extern "C" void kernel_launch(void* const* d_in, const int* in_sizes, int n_in,
                              void* d_out, int out_size, void* d_ws, size_t ws_size,
                              hipStream_t stream)
{
  const float* query  = (const float*)d_in[0];
  const float* key    = (const float*)d_in[1];
  const int*   mask   = (const int*)d_in[2];
  const float* value1 = (const float*)d_in[3];
  const float* value2 = (const float*)d_in[4];
  const float* Wq  = (const float*)d_in[5];
  const float* bq  = (const float*)d_in[6];
  const float* gqw = (const float*)d_in[7];
  const float* gqb = (const float*)d_in[8];
  const float* Wk  = (const float*)d_in[9];
  const float* bk  = (const float*)d_in[10];
  const float* gkw = (const float*)d_in[11];
  const float* gkb = (const float*)d_in[12];
  const float* Wv1 = (const float*)d_in[13];
  const float* bv1 = (const float*)d_in[14];
  const float* gv1w= (const float*)d_in[15];
  const float* gv1b= (const float*)d_in[16];
  const float* Wv2 = (const float*)d_in[17];
  const float* bv2 = (const float*)d_in[18];
  const float* gv2w= (const float*)d_in[19];
  const float* gv2b= (const float*)d_in[20];
  const float* Wb  = (const float*)d_in[21];
  const float* bb  = (const float*)d_in[22];
  const float* Ws  = (const float*)d_in[23];
  const float* bs  = (const float*)d_in[24];
  const float* Wc  = (const float*)d_in[25];
  const float* bc  = (const float*)d_in[26];

  const size_t NK = (size_t)B_ * M_;           // 50176 rows
  u16* kout  = (u16*)d_ws;
  u16* v2out = kout  + NK * E_;
  u16* qout  = v2out + NK * E_;
  u16* v1out = qout  + (size_t)B_ * E_;
  u16* Wt    = v1out + (size_t)B_ * E_;        // 4 * 1024*1024 bf16

  dim3 g0(16, 16, 4);
  wconv_kernel<<<g0, 256, 0, stream>>>(Wq, Wk, Wv1, Wv2, Wt);

  dim3 g1(8, 788);
  proj_kernel<<<g1, 256, 0, stream>>>(query, key, value1, value2,
      bq, gqw, gqb, bk, gkw, gkb, bv1, gv1w, gv1b, bv2, gv2w, gv2b,
      Wt, qout, kout, v1out, v2out);

  dim3 g2(H_, B_);
  attn_kernel<<<g2, 256, 0, stream>>>(qout, kout, v1out, v2out, mask,
      Wb, bb, Ws, bs, Wc, bc, (float*)d_out);
}

// Round 2
// 888.925 us; speedup vs baseline: 1.2128x; 1.2128x over previous
//
#include <hip/hip_runtime.h>

typedef unsigned short u16;
typedef unsigned int u32;
typedef __attribute__((ext_vector_type(8))) short short8;
typedef __attribute__((ext_vector_type(4))) float floatx4;

#define E_ 1024
#define B_ 256
#define M_ 196
#define H_ 8
#define DH_ 128
#define MID_ 64

__device__ __forceinline__ u16 f2bf(float f){
  union { float f; u32 u; } v; v.f = f;
  return (u16)((v.u + (((v.u >> 16) & 1u) + 0x7fffu)) >> 16);
}
__device__ __forceinline__ float bf2f(u16 h){
  union { u32 u; float f; } v; v.u = ((u32)h) << 16;
  return v.f;
}
// pack two floats to bf16x2 (round-half-away via +0x8000, then take hi16s)
__device__ __forceinline__ u32 pack_bf2(float a, float b){
  u32 ua = __float_as_uint(a) + 0x8000u;
  u32 ub = __float_as_uint(b) + 0x8000u;
  return __builtin_amdgcn_perm(ub, ua, 0x07060302);
}
// async global->LDS, 16B per lane; LDS dest = base + lane*16 (wave-uniform base)
__device__ __forceinline__ void gl_lds16(const void* g, void* l){
  __builtin_amdgcn_global_load_lds(
      (const __attribute__((address_space(1))) u32*)g,
      (__attribute__((address_space(3))) u32*)l, 16, 0, 0);
}

// ---------------------------------------------------------------------------
// Kernel 0: convert+transpose the 4 projection weight matrices to bf16 [col][k].
// ---------------------------------------------------------------------------
__global__ __launch_bounds__(256) void wconv_kernel(
    const float* __restrict__ Wq, const float* __restrict__ Wk,
    const float* __restrict__ Wv1, const float* __restrict__ Wv2,
    u16* __restrict__ Wt)
{
  __shared__ u16 tile[64][72];
  const float* W = (blockIdx.z == 0) ? Wq : (blockIdx.z == 1) ? Wk
                 : (blockIdx.z == 2) ? Wv1 : Wv2;
  u16* out = Wt + (size_t)blockIdx.z * (E_ * E_);
  int k0 = blockIdx.x * 64, c0 = blockIdx.y * 64;
  int tx = threadIdx.x & 63, ty = threadIdx.x >> 6;
  #pragma unroll
  for (int i = 0; i < 16; i++){
    int k = ty * 16 + i;
    tile[k][tx] = f2bf(W[(size_t)(k0 + k) * E_ + c0 + tx]);
  }
  __syncthreads();
  #pragma unroll
  for (int i = 0; i < 16; i++){
    int c = ty * 16 + i;
    out[(size_t)(c0 + c) * E_ + k0 + tx] = tile[tx][c];
  }
}

// ---------------------------------------------------------------------------
// Kernel 1: fused GEMM + bias + celu + group-norm. 128x256 tile, BK=32,
// 4 waves, each wave owns 64 rows x 128 cols (= one full groupnorm group),
// 4x8 frags of 16x16x32 bf16 MFMA. Both operands staged via global_load_lds
// (16B): A fp32 with XOR chunk swizzle (slot = chunk ^ (row&7)) for
// conflict-free frag reads, B bf16 [col][32] (m97 contiguous-1KB pattern).
// A frags converted fp32->bf16 in-register with +0x8000 + v_perm pack.
// ---------------------------------------------------------------------------
__global__ __launch_bounds__(256, 2) void proj_kernel(
    const float* __restrict__ query, const float* __restrict__ key,
    const float* __restrict__ value1, const float* __restrict__ value2,
    const float* __restrict__ bq, const float* __restrict__ gqw, const float* __restrict__ gqb,
    const float* __restrict__ bk, const float* __restrict__ gkw, const float* __restrict__ gkb,
    const float* __restrict__ bv1, const float* __restrict__ gv1w, const float* __restrict__ gv1b,
    const float* __restrict__ bv2, const float* __restrict__ gv2w, const float* __restrict__ gv2b,
    const u16* __restrict__ Wt,
    u16* __restrict__ qout, u16* __restrict__ kout,
    u16* __restrict__ v1out, u16* __restrict__ v2out)
{
  __shared__ float a_lds[128 * 32];   // 16 KB, row stride 32 floats (128B)
  __shared__ u16  b_lds[256 * 32];    // 16 KB, col stride 32 bf16 (64B)

  const int tid = threadIdx.x;
  const int w = tid >> 6, lane = tid & 63, qd = lane >> 4, lr = lane & 15;
  const int rh = w >> 1, ch = w & 1;

  const int mtb = blockIdx.y;
  const float* X; const float *bias, *gw, *gb; u16* out; int row0, matsel;
  if (mtb < 392)      { X = key;    bias = bk;  gw = gkw;  gb = gkb;  out = kout;  row0 = mtb * 128;         matsel = 1; }
  else if (mtb < 784) { X = value2; bias = bv2; gw = gv2w; gb = gv2b; out = v2out; row0 = (mtb - 392) * 128; matsel = 3; }
  else if (mtb < 786) { X = query;  bias = bq;  gw = gqw;  gb = gqb;  out = qout;  row0 = (mtb - 784) * 128; matsel = 0; }
  else                { X = value1; bias = bv1; gw = gv1w; gb = gv1b; out = v1out; row0 = (mtb - 786) * 128; matsel = 2; }
  const int col0 = blockIdx.x * 256;

  // A staging: call c (0..3) covers tile rows [w*32+c*8, +8), lane l -> row +(l>>3),
  // chunk slot l&7 holds global chunk (l&7)^(l>>3)  (row&7 == l>>3 here).
  const int arow_l = w * 32 + (lane >> 3);
  const int aswz   = ((lane & 7) ^ (lane >> 3)) * 4;      // float offset in row
  const float* aSrc = X + (size_t)(row0 + arow_l) * E_ + aswz;
  // B staging: call c covers tile cols [w*64+c*16, +16), lane l -> col +(l>>2),
  // k-chunk (l&3)*8 bf16.
  const int bcol_l = w * 64 + (lane >> 2);
  const u16* bSrc = Wt + (size_t)matsel * (E_ * E_) + (size_t)(col0 + bcol_l) * E_ + (lane & 3) * 8;

  floatx4 acc[4][8];
  #pragma unroll
  for (int i = 0; i < 4; i++)
    #pragma unroll
    for (int j = 0; j < 8; j++){
      floatx4 z = {0.f, 0.f, 0.f, 0.f};
      acc[i][j] = z;
    }

  for (int kt = 0; kt < 32; kt++){
    const int k0 = kt * 32;
    __syncthreads();
    #pragma unroll
    for (int c = 0; c < 4; c++)
      gl_lds16(aSrc + (size_t)c * 8 * E_ + k0, &a_lds[(w * 32 + c * 8) * 32]);
    #pragma unroll
    for (int c = 0; c < 4; c++)
      gl_lds16(bSrc + (size_t)c * 16 * E_ + k0, &b_lds[(w * 64 + c * 16) * 32]);
    __syncthreads();

    short8 bfr[8];
    #pragma unroll
    for (int nt = 0; nt < 8; nt++)
      bfr[nt] = *(const short8*)&b_lds[(ch * 128 + nt * 16 + lr) * 32 + qd * 8];

    const int sw = lr & 7;
    #pragma unroll
    for (int m2 = 0; m2 < 4; m2++){
      const int row = rh * 64 + m2 * 16 + lr;
      float4 f0 = *(const float4*)&a_lds[row * 32 + (((qd << 1)    ) ^ sw) * 4];
      float4 f1 = *(const float4*)&a_lds[row * 32 + (((qd << 1) | 1) ^ sw) * 4];
      union { u32 u[4]; short8 s; } af;
      af.u[0] = pack_bf2(f0.x, f0.y);
      af.u[1] = pack_bf2(f0.z, f0.w);
      af.u[2] = pack_bf2(f1.x, f1.y);
      af.u[3] = pack_bf2(f1.z, f1.w);
      #pragma unroll
      for (int nt = 0; nt < 8; nt++)
        acc[m2][nt] = __builtin_amdgcn_mfma_f32_16x16x32_bf16(af.s, bfr[nt], acc[m2][nt], 0, 0, 0);
    }
  }

  // Epilogue: bias + celu, per-row mean/var over this wave's 128-col group
  // (reduction entirely within the 16-lane lr group — no LDS needed).
  float biasv[8], gwv[8], gbv[8];
  #pragma unroll
  for (int nt = 0; nt < 8; nt++){
    int c = col0 + ch * 128 + nt * 16 + lr;
    biasv[nt] = bias[c]; gwv[nt] = gw[c]; gbv[nt] = gb[c];
  }
  #pragma unroll
  for (int m2 = 0; m2 < 4; m2++){
    #pragma unroll
    for (int r = 0; r < 4; r++){
      float s = 0.f, s2 = 0.f;
      #pragma unroll
      for (int nt = 0; nt < 8; nt++){
        float x = acc[m2][nt][r] + biasv[nt];
        x = (x > 0.f) ? x : 1.3f * expm1f(x * (1.0f / 1.3f));
        acc[m2][nt][r] = x;
        s += x; s2 += x * x;
      }
      #pragma unroll
      for (int off = 1; off < 16; off <<= 1){
        s  += __shfl_xor(s,  off, 64);
        s2 += __shfl_xor(s2, off, 64);
      }
      float mean = s * 0.0078125f;
      float var  = s2 * 0.0078125f - mean * mean;
      float rstd = rsqrtf(var + 1e-5f);
      size_t base = (size_t)(row0 + rh * 64 + m2 * 16 + qd * 4 + r) * E_ + col0 + ch * 128;
      #pragma unroll
      for (int nt = 0; nt < 8; nt++)
        out[base + nt * 16 + lr] = f2bf((acc[m2][nt][r] - mean) * rstd * gwv[nt] + gbv[nt]);
    }
  }
}

// ---------------------------------------------------------------------------
// Kernel 2: per-(b,h) attention. hidden = relu(kproj @ (diag(q)Wb) + bb):
// B' = diag(q)Wb built in LDS (17KB), A-frags straight from global (no att
// buffer). Logits + masked hidden-sums reduced in-register; masked softmax;
// vectorized v2 pooling (uint4/lane); sigmoid channel gate.
// ---------------------------------------------------------------------------
__global__ __launch_bounds__(256) void attn_kernel(
    const u16* __restrict__ qproj, const u16* __restrict__ kproj,
    const u16* __restrict__ v1proj, const u16* __restrict__ v2proj,
    const int* __restrict__ mask,
    const float* __restrict__ Wb, const float* __restrict__ bb,
    const float* __restrict__ Ws, const float* __restrict__ bs,
    const float* __restrict__ Wc, const float* __restrict__ bc,
    float* __restrict__ outp)
{
  __shared__ u16 wbt[64 * 136];      // B' = diag(q)*Wb, [n][k], stride 136
  __shared__ float qv[128];
  __shared__ float mrow[208];
  __shared__ float logitv[208];
  __shared__ float hsum_l[4][64];
  __shared__ float wexpv[208];
  __shared__ float poolv[64];
  __shared__ float v2acc[4][128];
  __shared__ float red[8];

  const int tid = threadIdx.x;
  const int w = tid >> 6, lane = tid & 63, qd = lane >> 4, lr = lane & 15;
  const int b = blockIdx.y, h = blockIdx.x;

  const u16* kbase  = kproj  + (size_t)b * M_ * E_ + h * DH_;
  const u16* v2base = v2proj + (size_t)b * M_ * E_ + h * DH_;

  if (tid < 128) qv[tid] = bf2f(qproj[(size_t)b * E_ + h * DH_ + tid]);
  if (tid < 208) mrow[tid] = (tid < M_) ? (float)mask[b * M_ + tid] : 0.f;
  __syncthreads();

  {
    int n = tid & 63, kb = (tid >> 6) * 32;
    #pragma unroll
    for (int kk = 0; kk < 32; kk++)
      wbt[n * 136 + kb + kk] = f2bf(qv[kb + kk] * Wb[(kb + kk) * MID_ + n]);
  }
  __syncthreads();

  float wsv[4], bbv[4];
  #pragma unroll
  for (int nt = 0; nt < 4; nt++){ wsv[nt] = Ws[nt * 16 + lr]; bbv[nt] = bb[nt * 16 + lr]; }
  const float bsv = bs[0];
  float hs[4] = {0, 0, 0, 0};

  for (int mt = w; mt < 13; mt += 4){
    int mrow_g = mt * 16 + lr;
    int mcl = (mrow_g < M_) ? mrow_g : (M_ - 1);   // clamp padded rows
    const u16* arow = kbase + (size_t)mcl * E_;
    floatx4 hacc[4];
    #pragma unroll
    for (int nt = 0; nt < 4; nt++){ floatx4 z = {0.f, 0.f, 0.f, 0.f}; hacc[nt] = z; }
    #pragma unroll
    for (int kc = 0; kc < 4; kc++){
      short8 afr = *(const short8*)(arow + kc * 32 + qd * 8);
      #pragma unroll
      for (int nt = 0; nt < 4; nt++){
        short8 bfr = *(const short8*)&wbt[(nt * 16 + lr) * 136 + kc * 32 + qd * 8];
        hacc[nt] = __builtin_amdgcn_mfma_f32_16x16x32_bf16(afr, bfr, hacc[nt], 0, 0, 0);
      }
    }
    float lp[4] = {0, 0, 0, 0};
    #pragma unroll
    for (int nt = 0; nt < 4; nt++){
      #pragma unroll
      for (int r = 0; r < 4; r++){
        float hv = hacc[nt][r] + bbv[nt];
        hv = fmaxf(hv, 0.f);
        lp[r] += hv * wsv[nt];
        hs[nt] += mrow[mt * 16 + qd * 4 + r] * hv;
      }
    }
    #pragma unroll
    for (int r = 0; r < 4; r++){
      float a = lp[r];
      #pragma unroll
      for (int off = 1; off < 16; off <<= 1) a += __shfl_xor(a, off, 64);
      if (lr == 0) logitv[mt * 16 + qd * 4 + r] = a + bsv;
    }
  }
  #pragma unroll
  for (int nt = 0; nt < 4; nt++){
    hs[nt] += __shfl_xor(hs[nt], 16, 64);
    hs[nt] += __shfl_xor(hs[nt], 32, 64);
  }
  if (lane < 16){
    #pragma unroll
    for (int nt = 0; nt < 4; nt++) hsum_l[w][nt * 16 + lane] = hs[nt];
  }
  __syncthreads();

  if (w == 0){
    float s = 0.f;
    for (int m = lane; m < M_; m += 64) s += mrow[m];
    #pragma unroll
    for (int off = 1; off < 64; off <<= 1) s += __shfl_xor(s, off, 64);
    if (lane == 0) red[0] = s;
  } else if (w == 1){
    float mx = -1e30f;
    for (int m = lane; m < M_; m += 64) if (mrow[m] > 0.5f) mx = fmaxf(mx, logitv[m]);
    #pragma unroll
    for (int off = 1; off < 64; off <<= 1) mx = fmaxf(mx, __shfl_xor(mx, off, 64));
    if (lane == 0) red[1] = mx;
  } else if (w == 2){
    poolv[lane & 63] = hsum_l[0][lane & 63] + hsum_l[1][lane & 63]
                     + hsum_l[2][lane & 63] + hsum_l[3][lane & 63];
  }
  __syncthreads();
  const float cnt = red[0], mx = red[1];
  if (tid < 208)
    wexpv[tid] = (tid < M_ && mrow[tid] > 0.5f) ? expf(logitv[tid] - mx) : 0.f;
  __syncthreads();
  if (w == 0){
    float s = 0.f;
    for (int m = lane; m < M_; m += 64) s += wexpv[m];
    #pragma unroll
    for (int off = 1; off < 64; off <<= 1) s += __shfl_xor(s, off, 64);
    if (lane == 0) red[2] = s;
  } else if (w == 1){
    poolv[lane & 63] = poolv[lane & 63] / cnt;
  }
  __syncthreads();
  const float S = red[2];

  // v2 pooling: per iteration a wave covers rows {it*16 + w*4 + qd}, 16B/lane.
  {
    float ac[8] = {0, 0, 0, 0, 0, 0, 0, 0};
    #pragma unroll
    for (int it = 0; it < 13; it++){
      int m = it * 16 + w * 4 + qd;
      if (m < M_){
        float we = wexpv[m];
        uint4 u = *(const uint4*)(v2base + (size_t)m * E_ + lr * 8);
        ac[0] += we * bf2f((u16)(u.x & 0xffff));
        ac[1] += we * bf2f((u16)(u.x >> 16));
        ac[2] += we * bf2f((u16)(u.y & 0xffff));
        ac[3] += we * bf2f((u16)(u.y >> 16));
        ac[4] += we * bf2f((u16)(u.z & 0xffff));
        ac[5] += we * bf2f((u16)(u.z >> 16));
        ac[6] += we * bf2f((u16)(u.w & 0xffff));
        ac[7] += we * bf2f((u16)(u.w >> 16));
      }
    }
    #pragma unroll
    for (int j = 0; j < 8; j++){
      ac[j] += __shfl_xor(ac[j], 16, 64);
      ac[j] += __shfl_xor(ac[j], 32, 64);
    }
    if (qd == 0){
      #pragma unroll
      for (int j = 0; j < 8; j++) v2acc[w][lr * 8 + j] = ac[j];
    }
  }
  __syncthreads();

  if (tid < 128){
    float a = 0.f;
    #pragma unroll 8
    for (int j = 0; j < 64; j++) a += poolv[j] * Wc[j * DH_ + tid];
    float acv = 1.f / (1.f + expf(-(a + bc[tid])));
    float vp = (v2acc[0][tid] + v2acc[1][tid] + v2acc[2][tid] + v2acc[3][tid]) / S;
    float o = bf2f(v1proj[(size_t)b * E_ + h * DH_ + tid]) * vp * acv;
    outp[(size_t)b * E_ + h * DH_ + tid] = o;
  }
}

// ---------------------------------------------------------------------------
extern "C" void kernel_launch(void* const* d_in, const int* in_sizes, int n_in,
                              void* d_out, int out_size, void* d_ws, size_t ws_size,
                              hipStream_t stream)
{
  const float* query  = (const float*)d_in[0];
  const float* key    = (const float*)d_in[1];
  const int*   mask   = (const int*)d_in[2];
  const float* value1 = (const float*)d_in[3];
  const float* value2 = (const float*)d_in[4];
  const float* Wq  = (const float*)d_in[5];
  const float* bq  = (const float*)d_in[6];
  const float* gqw = (const float*)d_in[7];
  const float* gqb = (const float*)d_in[8];
  const float* Wk  = (const float*)d_in[9];
  const float* bk  = (const float*)d_in[10];
  const float* gkw = (const float*)d_in[11];
  const float* gkb = (const float*)d_in[12];
  const float* Wv1 = (const float*)d_in[13];
  const float* bv1 = (const float*)d_in[14];
  const float* gv1w= (const float*)d_in[15];
  const float* gv1b= (const float*)d_in[16];
  const float* Wv2 = (const float*)d_in[17];
  const float* bv2 = (const float*)d_in[18];
  const float* gv2w= (const float*)d_in[19];
  const float* gv2b= (const float*)d_in[20];
  const float* Wb  = (const float*)d_in[21];
  const float* bb  = (const float*)d_in[22];
  const float* Ws  = (const float*)d_in[23];
  const float* bs  = (const float*)d_in[24];
  const float* Wc  = (const float*)d_in[25];
  const float* bc  = (const float*)d_in[26];

  const size_t NK = (size_t)B_ * M_;           // 50176 rows
  u16* kout  = (u16*)d_ws;
  u16* v2out = kout  + NK * E_;
  u16* qout  = v2out + NK * E_;
  u16* v1out = qout  + (size_t)B_ * E_;
  u16* Wt    = v1out + (size_t)B_ * E_;        // 4 * 1024*1024 bf16

  dim3 g0(16, 16, 4);
  wconv_kernel<<<g0, 256, 0, stream>>>(Wq, Wk, Wv1, Wv2, Wt);

  dim3 g1(4, 788);
  proj_kernel<<<g1, 256, 0, stream>>>(query, key, value1, value2,
      bq, gqw, gqb, bk, gkw, gkb, bv1, gv1w, gv1b, bv2, gv2w, gv2b,
      Wt, qout, kout, v1out, v2out);

  dim3 g2(H_, B_);
  attn_kernel<<<g2, 256, 0, stream>>>(qout, kout, v1out, v2out, mask,
      Wb, bb, Ws, bs, Wc, bc, (float*)d_out);
}